// Round 9
// baseline (259.088 us; speedup 1.0000x reference)
//
#include <hip/hip_runtime.h>
#include <math.h>

#define ORDER 32
#define T_DIM 1024
#define D4 256          // D/4 float4 columns
#define TCB 64          // t-rows per block
#define RPT 8           // t-rows per thread (512 thr: 64 d4-cols x 8 row-groups)

typedef float f32x4 __attribute__((ext_vector_type(4)));

// h[b,t,d] = sum_{j=0}^{31} w[j] * x[b, t-31+j, d] + thr ; out = (h>=0) ? 1 : 0
// float4 lanes (16B, coalescing sweet spot), 39-deep float4 register window,
// 8 outputs/thread, nontemporal stores (keep x resident in L2/L3).
// f32 fast path + rare f64 recompute when any |h| < 1e-3 (zero-flip req,
// validated absmax=0.0 in R1/R8).
__global__ __launch_bounds__(512)
void psn_kernel(const f32x4* __restrict__ x,
                const float* __restrict__ w,
                const float* __restrict__ thr_p,
                f32x4* __restrict__ out)
{
    const int d4     = blockIdx.x * 64 + (threadIdx.x & 63);  // 0..255
    const int tg     = threadIdx.x >> 6;                      // 0..7
    const int t_base = blockIdx.y * TCB + tg * RPT;
    const int b      = blockIdx.z;

    const float thr = thr_p[0];
    const size_t base = (size_t)b * T_DIM * D4 + d4;
    const f32x4* xb = x + base;
    f32x4*       ob = out + base;

    // Window: xv[i] = x4[b, t_base-31+i, d4], i in [0, RPT+31)
    f32x4 xv[RPT + ORDER - 1];
    if (t_base >= ORDER - 1) {
        const f32x4* p = xb + (size_t)(t_base - (ORDER - 1)) * D4;
        #pragma unroll
        for (int i = 0; i < RPT + ORDER - 1; ++i)
            xv[i] = p[(size_t)i * D4];
    } else {
        #pragma unroll
        for (int i = 0; i < RPT + ORDER - 1; ++i) {
            const int t = t_base - (ORDER - 1) + i;
            if (t >= 0) xv[i] = xb[(size_t)t * D4];
            else        xv[i] = (f32x4){0.0f, 0.0f, 0.0f, 0.0f};
        }
    }

    #pragma unroll
    for (int r = 0; r < RPT; ++r) {
        f32x4 h = {thr, thr, thr, thr};
        #pragma unroll
        for (int j = 0; j < ORDER; ++j) {
            const float wj = w[j];                 // uniform -> SGPR
            h[0] = fmaf(wj, xv[r + j][0], h[0]);
            h[1] = fmaf(wj, xv[r + j][1], h[1]);
            h[2] = fmaf(wj, xv[r + j][2], h[2]);
            h[3] = fmaf(wj, xv[r + j][3], h[3]);
        }

        f32x4 res;
        const bool near0 = (fabsf(h[0]) < 1e-3f) | (fabsf(h[1]) < 1e-3f) |
                           (fabsf(h[2]) < 1e-3f) | (fabsf(h[3]) < 1e-3f);
        if (__builtin_expect(near0, 0)) {
            // Boundary: recompute in f64 (f32*f32 products exact in f64).
            double d0 = (double)thr, d1 = (double)thr,
                   d2 = (double)thr, d3 = (double)thr;
            #pragma unroll
            for (int j = 0; j < ORDER; ++j) {
                const double wj = (double)w[j];
                d0 = fma(wj, (double)xv[r + j][0], d0);
                d1 = fma(wj, (double)xv[r + j][1], d1);
                d2 = fma(wj, (double)xv[r + j][2], d2);
                d3 = fma(wj, (double)xv[r + j][3], d3);
            }
            res[0] = (d0 >= 0.0) ? 1.0f : 0.0f;
            res[1] = (d1 >= 0.0) ? 1.0f : 0.0f;
            res[2] = (d2 >= 0.0) ? 1.0f : 0.0f;
            res[3] = (d3 >= 0.0) ? 1.0f : 0.0f;
        } else {
            res[0] = (h[0] >= 0.0f) ? 1.0f : 0.0f;
            res[1] = (h[1] >= 0.0f) ? 1.0f : 0.0f;
            res[2] = (h[2] >= 0.0f) ? 1.0f : 0.0f;
            res[3] = (h[3] >= 0.0f) ? 1.0f : 0.0f;
        }
        __builtin_nontemporal_store(res, &ob[(size_t)(t_base + r) * D4]);
    }
}

extern "C" void kernel_launch(void* const* d_in, const int* in_sizes, int n_in,
                              void* d_out, int out_size, void* d_ws, size_t ws_size,
                              hipStream_t stream)
{
    const f32x4* x   = (const f32x4*)d_in[0];
    const float* w   = (const float*)d_in[1];   // 32 taps
    const float* thr = (const float*)d_in[2];   // scalar (-1)
    f32x4* o = (f32x4*)d_out;

    dim3 grid(4, T_DIM / TCB, 16);              // (d4-tiles, t-chunks, B)
    psn_kernel<<<grid, 512, 0, stream>>>(x, w, thr, o);
}

// Round 10
// 218.195 us; speedup vs baseline: 1.1874x; 1.1874x over previous
//
#include <hip/hip_runtime.h>
#include <math.h>

#define ORDER 32
#define TC 32
#define PF 4
#define WLEN (TC + ORDER - 1)   // 63-deep rolling window

// h[b,t,d] = sum_{j=0}^{31} w[j] * x[b, t-31+j, d] + thr ; out = (h>=0) ? 1 : 0
// R1 structure (scalar lanes, TC=32, ideal 64MB fetch) + software pipeline:
// loads interleaved into the FMA loop at prefetch distance PF=4, register cap
// __launch_bounds__(256,6) (<=84 VGPR -> 24 waves/CU vs R1's 16). Peak live
// window ~36 f32 (xv[i] dies after h[i-31+...]); no spill expected.
// f32 fast path + rare f64 recompute when |h| < 1e-3 (zero-flip requirement;
// validated absmax=0.0 in R1/R8/R9).
__global__ __launch_bounds__(256, 6)
void psn_kernel(const float* __restrict__ x,
                const float* __restrict__ w,
                const float* __restrict__ thr_p,
                float* __restrict__ out)
{
    const int D = 1024;
    const int d  = blockIdx.x * 256 + threadIdx.x;           // 0..1023
    const int t0 = blockIdx.y * TC;
    const int b  = blockIdx.z;

    const float thr = thr_p[0];
    const size_t base = (size_t)b * 1024 * D + d;
    const float* xb = x + base;
    float*       ob = out + base;

    // xv[i] = x[b, t0-31+i, d]
    float xv[WLEN];

    // Prologue: 31-row halo + PF-deep prefetch (i in [0, 35)).
    // Guard needed for t0 < 31 blocks only (predicated, almost never taken).
    #pragma unroll
    for (int i = 0; i < ORDER - 1 + PF; ++i) {
        const int t = t0 - (ORDER - 1) + i;
        xv[i] = (t >= 0) ? xb[(size_t)t * D] : 0.0f;
    }

    #pragma unroll
    for (int tt = 0; tt < TC; ++tt) {
        // Interleaved prefetch: x[t0+tt+PF] -> xv[31+tt+PF]  (always in-bounds:
        // t <= t0+31 <= 1023, t >= 4).
        if (ORDER - 1 + tt + PF < WLEN)
            xv[ORDER - 1 + tt + PF] = xb[(size_t)(t0 + tt + PF) * D];

        float h = thr;
        #pragma unroll
        for (int j = 0; j < ORDER; ++j)
            h = fmaf(w[j], xv[tt + j], h);       // w[j] uniform -> SGPR

        float res;
        if (__builtin_expect(fabsf(h) < 1e-3f, 0)) {
            // Boundary: recompute in f64 (f32*f32 products exact in f64).
            double hd = (double)thr;
            #pragma unroll
            for (int j = 0; j < ORDER; ++j)
                hd = fma((double)w[j], (double)xv[tt + j], hd);
            res = (hd >= 0.0) ? 1.0f : 0.0f;
        } else {
            res = (h >= 0.0f) ? 1.0f : 0.0f;
        }
        ob[(size_t)(t0 + tt) * D] = res;         // interleaved store
    }
}

extern "C" void kernel_launch(void* const* d_in, const int* in_sizes, int n_in,
                              void* d_out, int out_size, void* d_ws, size_t ws_size,
                              hipStream_t stream)
{
    const float* x   = (const float*)d_in[0];
    const float* w   = (const float*)d_in[1];   // 32 taps
    const float* thr = (const float*)d_in[2];   // scalar (-1)
    float* o = (float*)d_out;

    dim3 grid(1024 / 256, 1024 / TC, 16);       // (d-tiles, t-chunks, B) = 2048 blocks
    psn_kernel<<<grid, 256, 0, stream>>>(x, w, thr, o);
}